// Round 3
// baseline (602.201 us; speedup 1.0000x reference)
//
#include <hip/hip_runtime.h>
#include <hip/hip_bf16.h>
#include <math.h>

#define NB 128
#define NC 512
#define NT 256
#define NL 512
#define NG 32
#define SCALE2 0.04419417382415922f  // 1/sqrt(512)

typedef __attribute__((ext_vector_type(8))) short bf16x8;
typedef __attribute__((ext_vector_type(4))) float f32x4;
typedef __attribute__((ext_vector_type(4))) unsigned short u16x4;
typedef __attribute__((ext_vector_type(8))) unsigned short u16x8;
typedef __hip_bfloat16 bf16;

struct Params {
  const float *x, *morph, *qkvb, *ekvb, *projb;
  const bf16 *wq, *we, *wp;
  bf16 *hT, *mT, *qT, *kfT, *vf;
  float *out;
  int b0;
};

enum { M_QKV = 0, M_EKV = 1 };

__device__ inline unsigned short f2bf_bits(float f) {
  bf16 h = __float2bfloat16(f);
  return *reinterpret_cast<unsigned short*>(&h);
}

// Async global->LDS, 16 B per lane; LDS dest wave-uniform, lane l -> lds+l*16.
__device__ inline void gld16(const void* g, void* lds) {
  __builtin_amdgcn_global_load_lds(
      (const __attribute__((address_space(1))) unsigned int*)g,
      (__attribute__((address_space(3))) unsigned int*)lds, 16, 0, 0);
}

// ---------------- GroupNorm statistics (float4 loads) ----------------
__global__ __launch_bounds__(256) void gn_stats_k(const float* __restrict__ x,
                                                  float* __restrict__ stats) {
  const int bg = blockIdx.x;                    // b*32+g; group = 4096 contiguous
  const float4* p4 = (const float4*)(x + (size_t)bg * 4096);
  float s = 0.f, s2 = 0.f;
  #pragma unroll
  for (int i = 0; i < 4; ++i) {
    float4 v = p4[threadIdx.x + i * 256];
    s  += v.x + v.y + v.z + v.w;
    s2 += v.x * v.x + v.y * v.y + v.z * v.z + v.w * v.w;
  }
  #pragma unroll
  for (int off = 32; off; off >>= 1) {
    s  += __shfl_down(s, off);
    s2 += __shfl_down(s2, off);
  }
  __shared__ float red[8];
  const int wave = threadIdx.x >> 6, lane = threadIdx.x & 63;
  if (lane == 0) { red[wave * 2] = s; red[wave * 2 + 1] = s2; }
  __syncthreads();
  if (threadIdx.x == 0) {
    float S = 0.f, S2 = 0.f;
    for (int w = 0; w < 4; ++w) { S += red[w * 2]; S2 += red[w * 2 + 1]; }
    float mu = S * (1.0f / 4096.0f);
    float var = S2 * (1.0f / 4096.0f) - mu * mu;
    stats[bg * 2]     = mu;
    stats[bg * 2 + 1] = rsqrtf(var + 1e-5f);
  }
}

// ---------------- fp32 -> bf16 weight conversion ----------------
__global__ __launch_bounds__(256) void cvt_k(const float* __restrict__ s,
                                             bf16* __restrict__ d, int n) {
  int i = blockIdx.x * 256 + threadIdx.x;
  if (i < n) d[i] = __float2bfloat16(s[i]);
}

// -------- merged [C][T] fp32 -> [T][C] bf16 transpose, 64x64 tiles ---------
// z < nbc: x with groupnorm -> hT ; z >= nbc: morph -> mT.
__global__ __launch_bounds__(256) void transpose2_k(const float* __restrict__ x,
                                                    const float* __restrict__ morph,
                                                    bf16* __restrict__ hT,
                                                    bf16* __restrict__ mT,
                                                    const float* __restrict__ stats,
                                                    const float* __restrict__ gnw,
                                                    const float* __restrict__ gnb,
                                                    int b0, int nbc) {
  __shared__ float sm[64][65];
  const int z = blockIdx.z;
  const int norm = (z < nbc) ? 1 : 0;
  const int lb = norm ? z : z - nbc;
  const int gb = b0 + lb;
  const float* src = norm ? x : morph;
  bf16* dst = norm ? hT : mT;
  const int t0 = blockIdx.x * 64, c0 = blockIdx.y * 64;
  const int tx = threadIdx.x & 15, ty = threadIdx.x >> 4;  // tx: t-quad, ty: 16 c
  #pragma unroll
  for (int ci = 0; ci < 4; ++ci) {
    const int c = ty + ci * 16;
    const int cg = c0 + c;
    float4 v = *(const float4*)&src[((size_t)gb * NC + cg) * NT + t0 + tx * 4];
    if (norm) {
      float mu = stats[(gb * NG + (cg >> 4)) * 2];
      float rs = stats[(gb * NG + (cg >> 4)) * 2 + 1];
      float wv = gnw[cg], bv = gnb[cg];
      v.x = (v.x - mu) * rs * wv + bv;
      v.y = (v.y - mu) * rs * wv + bv;
      v.z = (v.z - mu) * rs * wv + bv;
      v.w = (v.w - mu) * rs * wv + bv;
    }
    sm[c][tx * 4 + 0] = v.x; sm[c][tx * 4 + 1] = v.y;
    sm[c][tx * 4 + 2] = v.z; sm[c][tx * 4 + 3] = v.w;
  }
  __syncthreads();
  const int t = threadIdx.x >> 2, cq = threadIdx.x & 3;   // 16 contiguous c/thread
  u16x8 pk0, pk1;
  #pragma unroll
  for (int k = 0; k < 8; ++k) pk0[k] = f2bf_bits(sm[cq * 16 + k][t]);
  #pragma unroll
  for (int k = 0; k < 8; ++k) pk1[k] = f2bf_bits(sm[cq * 16 + 8 + k][t]);
  bf16* d = dst + ((size_t)lb * NT + t0 + t) * NC + c0 + cq * 16;
  *(u16x8*)d = pk0;
  *(u16x8*)(d + 8) = pk1;
}

// ------- MFMA GEMM (QKV / EKV): C[i][j] = sum_k A[i][k] * B[j][k] ----------
// Grid: (nbc, M/128, N/128) — batch in x for XCD L2 locality.
template <int MODE>
__global__ __launch_bounds__(256) void gemm_k(Params P) {
  __shared__ unsigned short As[128][32];
  __shared__ unsigned short Bs[128][32];
  const int lb = blockIdx.x;
  const int m0 = blockIdx.y * 128;
  const int n0 = blockIdx.z * 128;
  const int tid = threadIdx.x;
  const int lane = tid & 63, w = tid >> 6;
  const int wr = w >> 1, wc = w & 1;
  const int ln = lane & 15, kq = lane >> 4;

  const bf16 *Ab, *Bb;
  if (MODE == M_QKV) { Ab = P.hT + (size_t)lb * NT * NC; Bb = P.wq; }
  else               { Ab = P.mT + (size_t)lb * NT * NC; Bb = P.we; }

  const char* Abase = (const char*)(Ab + (size_t)m0 * 512);
  const char* Bbase = (const char*)(Bb + (size_t)n0 * 512);

  const int r_lo = w * 32 + (lane >> 2);
  const int cid16 = (lane & 3) * 16;

  f32x4 acc[4][4] = {};

  for (int k0 = 0; k0 < 512; k0 += 32) {
    const size_t kb = (size_t)k0 * 2 + cid16;
    #pragma unroll
    for (int h = 0; h < 2; ++h) {
      const int rw = r_lo + h * 16;
      gld16(Abase + (size_t)rw * 1024 + kb, (char*)As + w * 2048 + h * 1024);
      gld16(Bbase + (size_t)rw * 1024 + kb, (char*)Bs + w * 2048 + h * 1024);
    }
    __syncthreads();
    bf16x8 af[4], bfr[4];
    #pragma unroll
    for (int i = 0; i < 4; ++i)
      af[i] = *(const bf16x8*)&As[wr * 64 + i * 16 + ln][kq * 8];
    #pragma unroll
    for (int j = 0; j < 4; ++j)
      bfr[j] = *(const bf16x8*)&Bs[wc * 64 + j * 16 + ln][kq * 8];
    #pragma unroll
    for (int i = 0; i < 4; ++i)
      #pragma unroll
      for (int j = 0; j < 4; ++j)
        acc[i][j] = __builtin_amdgcn_mfma_f32_16x16x32_bf16(af[i], bfr[j], acc[i][j], 0, 0, 0);
    __syncthreads();
  }

  #pragma unroll
  for (int i = 0; i < 4; ++i) {
    const int ig = m0 + wr * 64 + i * 16 + kq * 4;
    #pragma unroll
    for (int j = 0; j < 4; ++j) {
      const int jg = n0 + wc * 64 + j * 16 + ln;
      f32x4 a = acc[i][j];
      if (MODE == M_QKV) {
        float bias = P.qkvb[jg];
        if (jg < 512) {
          bf16* d = P.qT + ((size_t)lb * NT + ig) * NC + jg;
          #pragma unroll
          for (int r = 0; r < 4; ++r) d[(size_t)r * NC] = __float2bfloat16(a[r] + bias);
        } else if (jg < 1024) {
          bf16* d = P.kfT + ((size_t)lb * NL + 256 + ig) * NC + (jg - 512);
          #pragma unroll
          for (int r = 0; r < 4; ++r) d[(size_t)r * NC] = __float2bfloat16(a[r] + bias);
        } else {
          u16x4 pk;
          #pragma unroll
          for (int r = 0; r < 4; ++r) pk[r] = f2bf_bits(a[r] + bias);
          *(u16x4*)(P.vf + ((size_t)lb * NC + (jg - 1024)) * NL + 256 + ig) = pk;
        }
      } else {  // M_EKV
        float bias = P.ekvb[jg];
        if (jg < 512) {
          bf16* d = P.kfT + ((size_t)lb * NL + ig) * NC + jg;
          #pragma unroll
          for (int r = 0; r < 4; ++r) d[(size_t)r * NC] = __float2bfloat16(a[r] + bias);
        } else {
          u16x4 pk;
          #pragma unroll
          for (int r = 0; r < 4; ++r) pk[r] = f2bf_bits(a[r] + bias);
          *(u16x4*)(P.vf + ((size_t)lb * NC + (jg - 512)) * NL + ig) = pk;
        }
      }
    }
  }
}

// ---------------- Fused attention: logits+softmax+PV+proj+residual ---------
// Grid (nbc, 8): block = (batch, 32-row Q-tile). 256 threads / 4 waves.
// Wave w owns column range [w*128, w*128+128) of every 512-wide stage.
// A/B MFMA fragments are loaded DIRECTLY from global (no LDS staging, no
// in-loop barriers): B rows are wave-exclusive (zero cross-wave reuse) and
// K/V/Wp are L2-resident (the 8 q-tile blocks of a batch map to one XCD:
// block ids differ by nbc which is a multiple of 8). LDS holds only the
// P/O transpose buffer + softmax reductions (34 KB -> 4 blocks/CU).
__global__ __launch_bounds__(256) void attn_k(Params P) {
  __shared__ unsigned short Pbuf[32][520];   // 33 KB  P / O roundtrip (pad 8)
  __shared__ float redm[4][32];
  __shared__ float reds[4][32];

  const int lb = blockIdx.x, gb = P.b0 + lb;
  const int t0 = blockIdx.y * 32;
  const int tid = threadIdx.x;
  const int lane = tid & 63, w = tid >> 6;
  const int ln = lane & 15, kq = lane >> 4;

  const bf16* qg  = P.qT  + ((size_t)lb * NT + t0) * NC;
  const bf16* kg  = P.kfT + (size_t)lb * NL * NC;
  const bf16* vg  = P.vf  + (size_t)lb * NC * NL;
  const bf16* wpg = P.wp;

  f32x4 sa[2][8] = {};
  bf16x8 af[2], bfr[8];

  // ---- Phase 1: S = q . kf^T  (frags straight from global) ----
  {
    const bf16* qa0 = qg + (size_t)ln * NC + kq * 8;
    const bf16* kb0 = kg + (size_t)(w * 128 + ln) * NC + kq * 8;
    for (int k0 = 0; k0 < 512; k0 += 32) {
      af[0] = *(const bf16x8*)(qa0 + k0);
      af[1] = *(const bf16x8*)(qa0 + (size_t)16 * NC + k0);
      #pragma unroll
      for (int j = 0; j < 8; ++j)
        bfr[j] = *(const bf16x8*)(kb0 + (size_t)j * 16 * NC + k0);
      #pragma unroll
      for (int i = 0; i < 2; ++i)
        #pragma unroll
        for (int j = 0; j < 8; ++j)
          sa[i][j] = __builtin_amdgcn_mfma_f32_16x16x32_bf16(af[i], bfr[j], sa[i][j], 0, 0, 0);
    }
  }

  // ---- softmax over L=512 (rows: i*16 + kq*4 + r) ----
  float mx[2][4], sum[2][4], inv[2][4];
  #pragma unroll
  for (int i = 0; i < 2; ++i)
    #pragma unroll
    for (int r = 0; r < 4; ++r) {
      float m = -1e30f;
      #pragma unroll
      for (int j = 0; j < 8; ++j) m = fmaxf(m, sa[i][j][r]);
      mx[i][r] = m;
    }
  #pragma unroll
  for (int off = 1; off < 16; off <<= 1)
    #pragma unroll
    for (int i = 0; i < 2; ++i)
      #pragma unroll
      for (int r = 0; r < 4; ++r) mx[i][r] = fmaxf(mx[i][r], __shfl_xor(mx[i][r], off));
  if (ln == 0)
    #pragma unroll
    for (int i = 0; i < 2; ++i)
      #pragma unroll
      for (int r = 0; r < 4; ++r) redm[w][i * 16 + kq * 4 + r] = mx[i][r];
  __syncthreads();
  #pragma unroll
  for (int i = 0; i < 2; ++i)
    #pragma unroll
    for (int r = 0; r < 4; ++r) {
      const int row = i * 16 + kq * 4 + r;
      mx[i][r] = fmaxf(fmaxf(redm[0][row], redm[1][row]),
                       fmaxf(redm[2][row], redm[3][row]));
      sum[i][r] = 0.f;
    }
  #pragma unroll
  for (int i = 0; i < 2; ++i)
    #pragma unroll
    for (int j = 0; j < 8; ++j)
      #pragma unroll
      for (int r = 0; r < 4; ++r) {
        float e = __expf(SCALE2 * (sa[i][j][r] - mx[i][r]));
        sa[i][j][r] = e;
        sum[i][r] += e;
      }
  #pragma unroll
  for (int off = 1; off < 16; off <<= 1)
    #pragma unroll
    for (int i = 0; i < 2; ++i)
      #pragma unroll
      for (int r = 0; r < 4; ++r) sum[i][r] += __shfl_xor(sum[i][r], off);
  if (ln == 0)
    #pragma unroll
    for (int i = 0; i < 2; ++i)
      #pragma unroll
      for (int r = 0; r < 4; ++r) reds[w][i * 16 + kq * 4 + r] = sum[i][r];
  __syncthreads();
  #pragma unroll
  for (int i = 0; i < 2; ++i)
    #pragma unroll
    for (int r = 0; r < 4; ++r) {
      const int row = i * 16 + kq * 4 + r;
      inv[i][r] = 1.0f / (reds[0][row] + reds[1][row] + reds[2][row] + reds[3][row]);
    }
  #pragma unroll
  for (int i = 0; i < 2; ++i)
    #pragma unroll
    for (int j = 0; j < 8; ++j)
      #pragma unroll
      for (int r = 0; r < 4; ++r)
        Pbuf[i * 16 + kq * 4 + r][w * 128 + j * 16 + ln] = f2bf_bits(sa[i][j][r] * inv[i][r]);
  __syncthreads();

  // ---- Phase 2: O = P . vf^T  (A from Pbuf, B straight from global) ----
  f32x4 oa[2][8] = {};
  {
    const bf16* vb0 = vg + (size_t)(w * 128 + ln) * NL + kq * 8;
    for (int k0 = 0; k0 < 512; k0 += 32) {
      af[0] = *(const bf16x8*)&Pbuf[ln][k0 + kq * 8];
      af[1] = *(const bf16x8*)&Pbuf[16 + ln][k0 + kq * 8];
      #pragma unroll
      for (int j = 0; j < 8; ++j)
        bfr[j] = *(const bf16x8*)(vb0 + (size_t)j * 16 * NL + k0);
      #pragma unroll
      for (int i = 0; i < 2; ++i)
        #pragma unroll
        for (int j = 0; j < 8; ++j)
          oa[i][j] = __builtin_amdgcn_mfma_f32_16x16x32_bf16(af[i], bfr[j], oa[i][j], 0, 0, 0);
    }
  }
  __syncthreads();   // all waves done reading P before overwrite

  // ---- O -> Pbuf (bf16) for phase 3 ----
  #pragma unroll
  for (int i = 0; i < 2; ++i)
    #pragma unroll
    for (int j = 0; j < 8; ++j)
      #pragma unroll
      for (int r = 0; r < 4; ++r)
        Pbuf[i * 16 + kq * 4 + r][w * 128 + j * 16 + ln] = f2bf_bits(oa[i][j][r]);
  __syncthreads();

  // ---- Phase 3: Z = O . wp^T  (A from Pbuf, B straight from global) ----
  f32x4 za[2][8] = {};
  {
    const bf16* wb0 = wpg + (size_t)(w * 128 + ln) * NC + kq * 8;
    for (int k0 = 0; k0 < 512; k0 += 32) {
      af[0] = *(const bf16x8*)&Pbuf[ln][k0 + kq * 8];
      af[1] = *(const bf16x8*)&Pbuf[16 + ln][k0 + kq * 8];
      #pragma unroll
      for (int j = 0; j < 8; ++j)
        bfr[j] = *(const bf16x8*)(wb0 + (size_t)j * 16 * NC + k0);
      #pragma unroll
      for (int i = 0; i < 2; ++i)
        #pragma unroll
        for (int j = 0; j < 8; ++j)
          za[i][j] = __builtin_amdgcn_mfma_f32_16x16x32_bf16(af[i], bfr[j], za[i][j], 0, 0, 0);
    }
  }

  // ---- epilogue: out[b][c][t] = 2*morph - x - (z + projb[c]) ----
  #pragma unroll
  for (int i = 0; i < 2; ++i) {
    const int trow = t0 + i * 16 + kq * 4;
    #pragma unroll
    for (int j = 0; j < 8; ++j) {
      const int c = w * 128 + j * 16 + ln;
      const float bias = P.projb[c];
      const size_t idx = ((size_t)gb * NC + c) * NT + trow;
      float4 mo = *(const float4*)&P.morph[idx];
      float4 xx = *(const float4*)&P.x[idx];
      f32x4 o;
      o[0] = 2.0f * mo.x - xx.x - (za[i][j][0] + bias);
      o[1] = 2.0f * mo.y - xx.y - (za[i][j][1] + bias);
      o[2] = 2.0f * mo.z - xx.z - (za[i][j][2] + bias);
      o[3] = 2.0f * mo.w - xx.w - (za[i][j][3] + bias);
      *(f32x4*)&P.out[idx] = o;
    }
  }
}

extern "C" void kernel_launch(void* const* d_in, const int* in_sizes, int n_in,
                              void* d_out, int out_size, void* d_ws, size_t ws_size,
                              hipStream_t stream) {
  const float* x     = (const float*)d_in[0];
  const float* morph = (const float*)d_in[1];
  const float* gnw   = (const float*)d_in[2];
  const float* gnb   = (const float*)d_in[3];
  const float* qkvw  = (const float*)d_in[4];
  const float* qkvb  = (const float*)d_in[5];
  const float* ekvw  = (const float*)d_in[6];
  const float* ekvb  = (const float*)d_in[7];
  const float* projw = (const float*)d_in[8];
  const float* projb = (const float*)d_in[9];

  bf16* wq = (bf16*)d_ws;                // 786432
  bf16* we = wq + 786432;                // 524288
  bf16* wp = we + 524288;                // 262144
  float* stats = (float*)(wp + 262144);  // 8192 floats
  bf16* pb = (bf16*)(stats + 8192);

  // Per-batch bf16: hT 131072 + mT 131072 + qT 131072 + kfT 262144 + vf 262144
  const size_t per_b = 917504;
  const size_t fixed = (size_t)(786432 + 524288 + 262144) * 2 + 8192 * 4;
  int nbc = NB;
  while (nbc > 1 && fixed + (size_t)nbc * per_b * 2 > ws_size) nbc >>= 1;

  Params P;
  P.x = x; P.morph = morph; P.qkvb = qkvb; P.ekvb = ekvb; P.projb = projb;
  P.wq = wq; P.we = we; P.wp = wp;
  P.hT  = pb;  pb += (size_t)nbc * 131072;
  P.mT  = pb;  pb += (size_t)nbc * 131072;
  P.qT  = pb;  pb += (size_t)nbc * 131072;
  P.kfT = pb;  pb += (size_t)nbc * 262144;
  P.vf  = pb;
  P.out = (float*)d_out;

  gn_stats_k<<<dim3(NB * NG), dim3(256), 0, stream>>>(x, stats);
  cvt_k<<<dim3(3072), dim3(256), 0, stream>>>(qkvw, wq, 786432);
  cvt_k<<<dim3(2048), dim3(256), 0, stream>>>(ekvw, we, 524288);
  cvt_k<<<dim3(1024), dim3(256), 0, stream>>>(projw, wp, 262144);

  for (int b0 = 0; b0 < NB; b0 += nbc) {
    P.b0 = b0;
    transpose2_k<<<dim3(4, 8, 2 * nbc), dim3(256), 0, stream>>>(
        x, morph, P.hT, P.mT, stats, gnw, gnb, b0, nbc);
    gemm_k<M_QKV><<<dim3(nbc, 2, 12), dim3(256), 0, stream>>>(P);
    gemm_k<M_EKV><<<dim3(nbc, 2, 8),  dim3(256), 0, stream>>>(P);
    attn_k       <<<dim3(nbc, 8),     dim3(256), 0, stream>>>(P);
  }
}

// Round 4
// 542.056 us; speedup vs baseline: 1.1110x; 1.1110x over previous
//
#include <hip/hip_runtime.h>
#include <hip/hip_bf16.h>
#include <math.h>

#define NB 128
#define NC 512
#define NT 256
#define NL 512
#define NG 32
#define SCALE2 0.04419417382415922f  // 1/sqrt(512)

typedef __attribute__((ext_vector_type(8))) short bf16x8;
typedef __attribute__((ext_vector_type(4))) float f32x4;
typedef __attribute__((ext_vector_type(4))) unsigned short u16x4;
typedef __attribute__((ext_vector_type(8))) unsigned short u16x8;
typedef __hip_bfloat16 bf16;

struct Params {
  const float *x, *morph, *qkvb, *ekvb, *projb;
  const bf16 *wq, *we, *wp;
  bf16 *hT, *mT, *qT, *kfT, *vf;
  float *out;
  int b0;
};

enum { M_QKV = 0, M_EKV = 1 };

__device__ inline unsigned short f2bf_bits(float f) {
  bf16 h = __float2bfloat16(f);
  return *reinterpret_cast<unsigned short*>(&h);
}

// Async global->LDS, 16 B per lane; LDS dest wave-uniform, lane l -> lds+l*16.
__device__ inline void gld16(const void* g, void* lds) {
  __builtin_amdgcn_global_load_lds(
      (const __attribute__((address_space(1))) unsigned int*)g,
      (__attribute__((address_space(3))) unsigned int*)lds, 16, 0, 0);
}

// ---------------- GroupNorm statistics (float4 loads) ----------------
__global__ __launch_bounds__(256) void gn_stats_k(const float* __restrict__ x,
                                                  float* __restrict__ stats) {
  const int bg = blockIdx.x;                    // b*32+g; group = 4096 contiguous
  const float4* p4 = (const float4*)(x + (size_t)bg * 4096);
  float s = 0.f, s2 = 0.f;
  #pragma unroll
  for (int i = 0; i < 4; ++i) {
    float4 v = p4[threadIdx.x + i * 256];
    s  += v.x + v.y + v.z + v.w;
    s2 += v.x * v.x + v.y * v.y + v.z * v.z + v.w * v.w;
  }
  #pragma unroll
  for (int off = 32; off; off >>= 1) {
    s  += __shfl_down(s, off);
    s2 += __shfl_down(s2, off);
  }
  __shared__ float red[8];
  const int wave = threadIdx.x >> 6, lane = threadIdx.x & 63;
  if (lane == 0) { red[wave * 2] = s; red[wave * 2 + 1] = s2; }
  __syncthreads();
  if (threadIdx.x == 0) {
    float S = 0.f, S2 = 0.f;
    for (int w = 0; w < 4; ++w) { S += red[w * 2]; S2 += red[w * 2 + 1]; }
    float mu = S * (1.0f / 4096.0f);
    float var = S2 * (1.0f / 4096.0f) - mu * mu;
    stats[bg * 2]     = mu;
    stats[bg * 2 + 1] = rsqrtf(var + 1e-5f);
  }
}

// ---------------- fp32 -> bf16 weight conversion ----------------
__global__ __launch_bounds__(256) void cvt_k(const float* __restrict__ s,
                                             bf16* __restrict__ d, int n) {
  int i = blockIdx.x * 256 + threadIdx.x;
  if (i < n) d[i] = __float2bfloat16(s[i]);
}

// -------- merged [C][T] fp32 -> [T][C] bf16 transpose, 64x64 tiles ---------
// z < nbc: x with groupnorm -> hT ; z >= nbc: morph -> mT.
__global__ __launch_bounds__(256) void transpose2_k(const float* __restrict__ x,
                                                    const float* __restrict__ morph,
                                                    bf16* __restrict__ hT,
                                                    bf16* __restrict__ mT,
                                                    const float* __restrict__ stats,
                                                    const float* __restrict__ gnw,
                                                    const float* __restrict__ gnb,
                                                    int b0, int nbc) {
  __shared__ float sm[64][65];
  const int z = blockIdx.z;
  const int norm = (z < nbc) ? 1 : 0;
  const int lb = norm ? z : z - nbc;
  const int gb = b0 + lb;
  const float* src = norm ? x : morph;
  bf16* dst = norm ? hT : mT;
  const int t0 = blockIdx.x * 64, c0 = blockIdx.y * 64;
  const int tx = threadIdx.x & 15, ty = threadIdx.x >> 4;  // tx: t-quad, ty: 16 c
  #pragma unroll
  for (int ci = 0; ci < 4; ++ci) {
    const int c = ty + ci * 16;
    const int cg = c0 + c;
    float4 v = *(const float4*)&src[((size_t)gb * NC + cg) * NT + t0 + tx * 4];
    if (norm) {
      float mu = stats[(gb * NG + (cg >> 4)) * 2];
      float rs = stats[(gb * NG + (cg >> 4)) * 2 + 1];
      float wv = gnw[cg], bv = gnb[cg];
      v.x = (v.x - mu) * rs * wv + bv;
      v.y = (v.y - mu) * rs * wv + bv;
      v.z = (v.z - mu) * rs * wv + bv;
      v.w = (v.w - mu) * rs * wv + bv;
    }
    sm[c][tx * 4 + 0] = v.x; sm[c][tx * 4 + 1] = v.y;
    sm[c][tx * 4 + 2] = v.z; sm[c][tx * 4 + 3] = v.w;
  }
  __syncthreads();
  const int t = threadIdx.x >> 2, cq = threadIdx.x & 3;   // 16 contiguous c/thread
  u16x8 pk0, pk1;
  #pragma unroll
  for (int k = 0; k < 8; ++k) pk0[k] = f2bf_bits(sm[cq * 16 + k][t]);
  #pragma unroll
  for (int k = 0; k < 8; ++k) pk1[k] = f2bf_bits(sm[cq * 16 + 8 + k][t]);
  bf16* d = dst + ((size_t)lb * NT + t0 + t) * NC + c0 + cq * 16;
  *(u16x8*)d = pk0;
  *(u16x8*)(d + 8) = pk1;
}

// ------- MFMA GEMM (QKV / EKV): C[i][j] = sum_k A[i][k] * B[j][k] ----------
// Grid: (nbc, M/128, N/128) — batch in x for XCD L2 locality.
template <int MODE>
__global__ __launch_bounds__(256) void gemm_k(Params P) {
  __shared__ unsigned short As[128][32];
  __shared__ unsigned short Bs[128][32];
  const int lb = blockIdx.x;
  const int m0 = blockIdx.y * 128;
  const int n0 = blockIdx.z * 128;
  const int tid = threadIdx.x;
  const int lane = tid & 63, w = tid >> 6;
  const int wr = w >> 1, wc = w & 1;
  const int ln = lane & 15, kq = lane >> 4;

  const bf16 *Ab, *Bb;
  if (MODE == M_QKV) { Ab = P.hT + (size_t)lb * NT * NC; Bb = P.wq; }
  else               { Ab = P.mT + (size_t)lb * NT * NC; Bb = P.we; }

  const char* Abase = (const char*)(Ab + (size_t)m0 * 512);
  const char* Bbase = (const char*)(Bb + (size_t)n0 * 512);

  const int r_lo = w * 32 + (lane >> 2);
  const int cid16 = (lane & 3) * 16;

  f32x4 acc[4][4] = {};

  for (int k0 = 0; k0 < 512; k0 += 32) {
    const size_t kb = (size_t)k0 * 2 + cid16;
    #pragma unroll
    for (int h = 0; h < 2; ++h) {
      const int rw = r_lo + h * 16;
      gld16(Abase + (size_t)rw * 1024 + kb, (char*)As + w * 2048 + h * 1024);
      gld16(Bbase + (size_t)rw * 1024 + kb, (char*)Bs + w * 2048 + h * 1024);
    }
    __syncthreads();
    bf16x8 af[4], bfr[4];
    #pragma unroll
    for (int i = 0; i < 4; ++i)
      af[i] = *(const bf16x8*)&As[wr * 64 + i * 16 + ln][kq * 8];
    #pragma unroll
    for (int j = 0; j < 4; ++j)
      bfr[j] = *(const bf16x8*)&Bs[wc * 64 + j * 16 + ln][kq * 8];
    #pragma unroll
    for (int i = 0; i < 4; ++i)
      #pragma unroll
      for (int j = 0; j < 4; ++j)
        acc[i][j] = __builtin_amdgcn_mfma_f32_16x16x32_bf16(af[i], bfr[j], acc[i][j], 0, 0, 0);
    __syncthreads();
  }

  #pragma unroll
  for (int i = 0; i < 4; ++i) {
    const int ig = m0 + wr * 64 + i * 16 + kq * 4;
    #pragma unroll
    for (int j = 0; j < 4; ++j) {
      const int jg = n0 + wc * 64 + j * 16 + ln;
      f32x4 a = acc[i][j];
      if (MODE == M_QKV) {
        float bias = P.qkvb[jg];
        if (jg < 512) {
          bf16* d = P.qT + ((size_t)lb * NT + ig) * NC + jg;
          #pragma unroll
          for (int r = 0; r < 4; ++r) d[(size_t)r * NC] = __float2bfloat16(a[r] + bias);
        } else if (jg < 1024) {
          bf16* d = P.kfT + ((size_t)lb * NL + 256 + ig) * NC + (jg - 512);
          #pragma unroll
          for (int r = 0; r < 4; ++r) d[(size_t)r * NC] = __float2bfloat16(a[r] + bias);
        } else {
          u16x4 pk;
          #pragma unroll
          for (int r = 0; r < 4; ++r) pk[r] = f2bf_bits(a[r] + bias);
          *(u16x4*)(P.vf + ((size_t)lb * NC + (jg - 1024)) * NL + 256 + ig) = pk;
        }
      } else {  // M_EKV
        float bias = P.ekvb[jg];
        if (jg < 512) {
          bf16* d = P.kfT + ((size_t)lb * NL + ig) * NC + jg;
          #pragma unroll
          for (int r = 0; r < 4; ++r) d[(size_t)r * NC] = __float2bfloat16(a[r] + bias);
        } else {
          u16x4 pk;
          #pragma unroll
          for (int r = 0; r < 4; ++r) pk[r] = f2bf_bits(a[r] + bias);
          *(u16x4*)(P.vf + ((size_t)lb * NC + (jg - 512)) * NL + ig) = pk;
        }
      }
    }
  }
}

// ---- Attention as 3 batched GEMMs (same proven skeleton) + softmax --------
// Buffer overlays (per b0-chunk, strictly ordered by stream serialization):
//   S  f32  [256][512]  -> over hT+mT   (dead after QKV/EKV gemms)
//   Pm bf16 [256][512]  -> over qT      (dead after gemm_att<0>)
//   O  bf16 [256][512]  -> over kfT     (dead after gemm_att<0>)
// MODE 0: S = qT . kfT^T          (f32 out)
// MODE 1: O = Pm . vf^T           (bf16 out)
// MODE 2: Z = O . wp^T, fused epilogue out = 2*morph - x - (Z + projb)
template <int MODE>
__global__ __launch_bounds__(256) void gemm_att(Params P) {
  __shared__ unsigned short As[128][32];
  __shared__ unsigned short Bs[128][32];
  const int lb = blockIdx.x;
  const int m0 = blockIdx.y * 128;   // t-tile (M = 256)
  const int n0 = blockIdx.z * 128;   // col tile (N = 512)
  const int tid = threadIdx.x;
  const int lane = tid & 63, w = tid >> 6;
  const int wr = w >> 1, wc = w & 1;
  const int ln = lane & 15, kq = lane >> 4;

  const bf16 *Ab, *Bb;
  if (MODE == 0)      { Ab = P.qT  + (size_t)lb * 131072; Bb = P.kfT + (size_t)lb * NL * NC; }
  else if (MODE == 1) { Ab = P.qT  + (size_t)lb * 131072; Bb = P.vf  + (size_t)lb * NC * NL; }
  else                { Ab = P.kfT + (size_t)lb * 262144; Bb = P.wp; }

  const char* Abase = (const char*)(Ab + (size_t)m0 * 512);
  const char* Bbase = (const char*)(Bb + (size_t)n0 * 512);

  const int r_lo = w * 32 + (lane >> 2);
  const int cid16 = (lane & 3) * 16;

  f32x4 acc[4][4] = {};

  for (int k0 = 0; k0 < 512; k0 += 32) {
    const size_t kb = (size_t)k0 * 2 + cid16;
    #pragma unroll
    for (int h = 0; h < 2; ++h) {
      const int rw = r_lo + h * 16;
      gld16(Abase + (size_t)rw * 1024 + kb, (char*)As + w * 2048 + h * 1024);
      gld16(Bbase + (size_t)rw * 1024 + kb, (char*)Bs + w * 2048 + h * 1024);
    }
    __syncthreads();
    bf16x8 af[4], bfr[4];
    #pragma unroll
    for (int i = 0; i < 4; ++i)
      af[i] = *(const bf16x8*)&As[wr * 64 + i * 16 + ln][kq * 8];
    #pragma unroll
    for (int j = 0; j < 4; ++j)
      bfr[j] = *(const bf16x8*)&Bs[wc * 64 + j * 16 + ln][kq * 8];
    #pragma unroll
    for (int i = 0; i < 4; ++i)
      #pragma unroll
      for (int j = 0; j < 4; ++j)
        acc[i][j] = __builtin_amdgcn_mfma_f32_16x16x32_bf16(af[i], bfr[j], acc[i][j], 0, 0, 0);
    __syncthreads();
  }

  float* Sg = (float*)P.hT + (size_t)lb * 131072;             // MODE 0 out
  bf16*  Og = P.kfT + (size_t)lb * 262144;                    // MODE 1 out
  const int gb = P.b0 + lb;                                   // MODE 2

  #pragma unroll
  for (int i = 0; i < 4; ++i) {
    const int ig = m0 + wr * 64 + i * 16 + kq * 4;
    #pragma unroll
    for (int j = 0; j < 4; ++j) {
      const int jg = n0 + wc * 64 + j * 16 + ln;
      f32x4 a = acc[i][j];
      if (MODE == 0) {
        #pragma unroll
        for (int r = 0; r < 4; ++r) Sg[(size_t)(ig + r) * NL + jg] = a[r];
      } else if (MODE == 1) {
        bf16* d = Og + (size_t)ig * NC + jg;
        #pragma unroll
        for (int r = 0; r < 4; ++r) d[(size_t)r * NC] = __float2bfloat16(a[r]);
      } else {
        const float bias = P.projb[jg];
        const size_t idx = ((size_t)gb * NC + jg) * NT + ig;
        float4 mo = *(const float4*)&P.morph[idx];
        float4 xx = *(const float4*)&P.x[idx];
        f32x4 o;
        o[0] = 2.0f * mo.x - xx.x - (a[0] + bias);
        o[1] = 2.0f * mo.y - xx.y - (a[1] + bias);
        o[2] = 2.0f * mo.z - xx.z - (a[2] + bias);
        o[3] = 2.0f * mo.w - xx.w - (a[3] + bias);
        *(f32x4*)&P.out[idx] = o;
      }
    }
  }
}

// ---- Row softmax over S (f32, rows of 512) -> P bf16 (overlays qT) --------
// One wave per row; lane holds 8 contiguous f32.
__global__ __launch_bounds__(256) void softmax_k(Params P) {
  const int row = blockIdx.x * 4 + (threadIdx.x >> 6);
  const int lane = threadIdx.x & 63;
  const int lb = row >> 8, t = row & 255;
  const float* src = (const float*)P.hT + (size_t)lb * 131072 + (size_t)t * NL + lane * 8;
  f32x4 a0 = ((const f32x4*)src)[0];
  f32x4 a1 = ((const f32x4*)src)[1];
  float v[8] = {a0[0], a0[1], a0[2], a0[3], a1[0], a1[1], a1[2], a1[3]};
  float m = v[0];
  #pragma unroll
  for (int k = 1; k < 8; ++k) m = fmaxf(m, v[k]);
  #pragma unroll
  for (int off = 1; off < 64; off <<= 1) m = fmaxf(m, __shfl_xor(m, off));
  float e[8], s = 0.f;
  #pragma unroll
  for (int k = 0; k < 8; ++k) { e[k] = __expf(SCALE2 * (v[k] - m)); s += e[k]; }
  #pragma unroll
  for (int off = 1; off < 64; off <<= 1) s += __shfl_xor(s, off);
  const float inv = 1.0f / s;
  u16x8 pk;
  #pragma unroll
  for (int k = 0; k < 8; ++k) pk[k] = f2bf_bits(e[k] * inv);
  bf16* dst = P.qT + (size_t)lb * 131072 + (size_t)t * NL + lane * 8;
  *(u16x8*)dst = pk;
}

extern "C" void kernel_launch(void* const* d_in, const int* in_sizes, int n_in,
                              void* d_out, int out_size, void* d_ws, size_t ws_size,
                              hipStream_t stream) {
  const float* x     = (const float*)d_in[0];
  const float* morph = (const float*)d_in[1];
  const float* gnw   = (const float*)d_in[2];
  const float* gnb   = (const float*)d_in[3];
  const float* qkvw  = (const float*)d_in[4];
  const float* qkvb  = (const float*)d_in[5];
  const float* ekvw  = (const float*)d_in[6];
  const float* ekvb  = (const float*)d_in[7];
  const float* projw = (const float*)d_in[8];
  const float* projb = (const float*)d_in[9];

  bf16* wq = (bf16*)d_ws;                // 786432
  bf16* we = wq + 786432;                // 524288
  bf16* wp = we + 524288;                // 262144
  float* stats = (float*)(wp + 262144);  // 8192 floats
  bf16* pb = (bf16*)(stats + 8192);

  // Per-batch bf16: hT 131072 + mT 131072 + qT 131072 + kfT 262144 + vf 262144
  const size_t per_b = 917504;
  const size_t fixed = (size_t)(786432 + 524288 + 262144) * 2 + 8192 * 4;
  int nbc = NB;
  while (nbc > 1 && fixed + (size_t)nbc * per_b * 2 > ws_size) nbc >>= 1;

  Params P;
  P.x = x; P.morph = morph; P.qkvb = qkvb; P.ekvb = ekvb; P.projb = projb;
  P.wq = wq; P.we = we; P.wp = wp;
  P.hT  = pb;  pb += (size_t)nbc * 131072;
  P.mT  = pb;  pb += (size_t)nbc * 131072;
  P.qT  = pb;  pb += (size_t)nbc * 131072;
  P.kfT = pb;  pb += (size_t)nbc * 262144;
  P.vf  = pb;
  P.out = (float*)d_out;

  gn_stats_k<<<dim3(NB * NG), dim3(256), 0, stream>>>(x, stats);
  cvt_k<<<dim3(3072), dim3(256), 0, stream>>>(qkvw, wq, 786432);
  cvt_k<<<dim3(2048), dim3(256), 0, stream>>>(ekvw, we, 524288);
  cvt_k<<<dim3(1024), dim3(256), 0, stream>>>(projw, wp, 262144);

  for (int b0 = 0; b0 < NB; b0 += nbc) {
    P.b0 = b0;
    transpose2_k<<<dim3(4, 8, 2 * nbc), dim3(256), 0, stream>>>(
        x, morph, P.hT, P.mT, stats, gnw, gnb, b0, nbc);
    gemm_k<M_QKV><<<dim3(nbc, 2, 12), dim3(256), 0, stream>>>(P);
    gemm_k<M_EKV><<<dim3(nbc, 2, 8),  dim3(256), 0, stream>>>(P);
    gemm_att<0>  <<<dim3(nbc, 2, 4),  dim3(256), 0, stream>>>(P);
    softmax_k    <<<dim3(nbc * 64),   dim3(256), 0, stream>>>(P);
    gemm_att<1>  <<<dim3(nbc, 2, 4),  dim3(256), 0, stream>>>(P);
    gemm_att<2>  <<<dim3(nbc, 2, 4),  dim3(256), 0, stream>>>(P);
  }
}

// Round 5
// 537.038 us; speedup vs baseline: 1.1213x; 1.0093x over previous
//
#include <hip/hip_runtime.h>
#include <hip/hip_bf16.h>
#include <math.h>

#define NB 128
#define NC 512
#define NT 256
#define NL 512
#define NG 32
#define SCALE2 0.04419417382415922f  // 1/sqrt(512)

typedef __attribute__((ext_vector_type(8))) short bf16x8;
typedef __attribute__((ext_vector_type(4))) float f32x4;
typedef __attribute__((ext_vector_type(4))) unsigned short u16x4;
typedef __attribute__((ext_vector_type(8))) unsigned short u16x8;
typedef __hip_bfloat16 bf16;

struct Params {
  const float *x, *morph, *qkvb, *ekvb, *projb;
  const bf16 *wq, *we, *wp;
  bf16 *hT, *mT, *qT, *kfT, *vf;
  float *out;
  int b0;
};

__device__ inline unsigned short f2bf_bits(float f) {
  bf16 h = __float2bfloat16(f);
  return *reinterpret_cast<unsigned short*>(&h);
}

// Async global->LDS, 16 B per lane; LDS dest wave-uniform, lane l -> lds+l*16.
__device__ inline void gld16(const void* g, void* lds) {
  __builtin_amdgcn_global_load_lds(
      (const __attribute__((address_space(1))) unsigned int*)g,
      (__attribute__((address_space(3))) unsigned int*)lds, 16, 0, 0);
}

// ---------------- GroupNorm statistics (float4 loads) ----------------
__global__ __launch_bounds__(256) void gn_stats_k(const float* __restrict__ x,
                                                  float* __restrict__ stats) {
  const int bg = blockIdx.x;                    // b*32+g; group = 4096 contiguous
  const float4* p4 = (const float4*)(x + (size_t)bg * 4096);
  float s = 0.f, s2 = 0.f;
  #pragma unroll
  for (int i = 0; i < 4; ++i) {
    float4 v = p4[threadIdx.x + i * 256];
    s  += v.x + v.y + v.z + v.w;
    s2 += v.x * v.x + v.y * v.y + v.z * v.z + v.w * v.w;
  }
  #pragma unroll
  for (int off = 32; off; off >>= 1) {
    s  += __shfl_down(s, off);
    s2 += __shfl_down(s2, off);
  }
  __shared__ float red[8];
  const int wave = threadIdx.x >> 6, lane = threadIdx.x & 63;
  if (lane == 0) { red[wave * 2] = s; red[wave * 2 + 1] = s2; }
  __syncthreads();
  if (threadIdx.x == 0) {
    float S = 0.f, S2 = 0.f;
    for (int w = 0; w < 4; ++w) { S += red[w * 2]; S2 += red[w * 2 + 1]; }
    float mu = S * (1.0f / 4096.0f);
    float var = S2 * (1.0f / 4096.0f) - mu * mu;
    stats[bg * 2]     = mu;
    stats[bg * 2 + 1] = rsqrtf(var + 1e-5f);
  }
}

// ---------------- fp32 -> bf16 weight conversion ----------------
__global__ __launch_bounds__(256) void cvt_k(const float* __restrict__ s,
                                             bf16* __restrict__ d, int n) {
  int i = blockIdx.x * 256 + threadIdx.x;
  if (i < n) d[i] = __float2bfloat16(s[i]);
}

// -------- merged [C][T] fp32 -> [T][C] bf16 transpose, 64x64 tiles ---------
// z < nbc: x with groupnorm -> hT ; z >= nbc: morph -> mT.
__global__ __launch_bounds__(256) void transpose2_k(const float* __restrict__ x,
                                                    const float* __restrict__ morph,
                                                    bf16* __restrict__ hT,
                                                    bf16* __restrict__ mT,
                                                    const float* __restrict__ stats,
                                                    const float* __restrict__ gnw,
                                                    const float* __restrict__ gnb,
                                                    int b0, int nbc) {
  __shared__ float sm[64][65];
  const int z = blockIdx.z;
  const int norm = (z < nbc) ? 1 : 0;
  const int lb = norm ? z : z - nbc;
  const int gb = b0 + lb;
  const float* src = norm ? x : morph;
  bf16* dst = norm ? hT : mT;
  const int t0 = blockIdx.x * 64, c0 = blockIdx.y * 64;
  const int tx = threadIdx.x & 15, ty = threadIdx.x >> 4;  // tx: t-quad, ty: 16 c
  #pragma unroll
  for (int ci = 0; ci < 4; ++ci) {
    const int c = ty + ci * 16;
    const int cg = c0 + c;
    float4 v = *(const float4*)&src[((size_t)gb * NC + cg) * NT + t0 + tx * 4];
    if (norm) {
      float mu = stats[(gb * NG + (cg >> 4)) * 2];
      float rs = stats[(gb * NG + (cg >> 4)) * 2 + 1];
      float wv = gnw[cg], bv = gnb[cg];
      v.x = (v.x - mu) * rs * wv + bv;
      v.y = (v.y - mu) * rs * wv + bv;
      v.z = (v.z - mu) * rs * wv + bv;
      v.w = (v.w - mu) * rs * wv + bv;
    }
    sm[c][tx * 4 + 0] = v.x; sm[c][tx * 4 + 1] = v.y;
    sm[c][tx * 4 + 2] = v.z; sm[c][tx * 4 + 3] = v.w;
  }
  __syncthreads();
  const int t = threadIdx.x >> 2, cq = threadIdx.x & 3;   // 16 contiguous c/thread
  u16x8 pk0, pk1;
  #pragma unroll
  for (int k = 0; k < 8; ++k) pk0[k] = f2bf_bits(sm[cq * 16 + k][t]);
  #pragma unroll
  for (int k = 0; k < 8; ++k) pk1[k] = f2bf_bits(sm[cq * 16 + 8 + k][t]);
  bf16* d = dst + ((size_t)lb * NT + t0 + t) * NC + c0 + cq * 16;
  *(u16x8*)d = pk0;
  *(u16x8*)(d + 8) = pk1;
}

// ---- Merged input GEMM (QKV + EKV in one dispatch) ------------------------
// Grid: (nbc, 2, 20). z<12: QKV n-tile z; z>=12: EKV n-tile z-12.
// C[i][j] = sum_k A[i][k] * B[j][k]; 128x128 tile, 2-barrier K-loop.
__global__ __launch_bounds__(256) void gemm_in_k(Params P) {
  __shared__ unsigned short As[128][32];
  __shared__ unsigned short Bs[128][32];
  const int lb = blockIdx.x;
  const int m0 = blockIdx.y * 128;
  const int z = blockIdx.z;
  const bool qkv = (z < 12);
  const int n0 = (qkv ? z : z - 12) * 128;
  const int tid = threadIdx.x;
  const int lane = tid & 63, w = tid >> 6;
  const int wr = w >> 1, wc = w & 1;
  const int ln = lane & 15, kq = lane >> 4;

  const bf16* Ab = (qkv ? P.hT : P.mT) + (size_t)lb * NT * NC;
  const bf16* Bb = qkv ? P.wq : P.we;

  const char* Abase = (const char*)(Ab + (size_t)m0 * 512);
  const char* Bbase = (const char*)(Bb + (size_t)n0 * 512);

  const int r_lo = w * 32 + (lane >> 2);
  const int cid16 = (lane & 3) * 16;

  f32x4 acc[4][4] = {};

  for (int k0 = 0; k0 < 512; k0 += 32) {
    const size_t kb = (size_t)k0 * 2 + cid16;
    #pragma unroll
    for (int h = 0; h < 2; ++h) {
      const int rw = r_lo + h * 16;
      gld16(Abase + (size_t)rw * 1024 + kb, (char*)As + w * 2048 + h * 1024);
      gld16(Bbase + (size_t)rw * 1024 + kb, (char*)Bs + w * 2048 + h * 1024);
    }
    __syncthreads();
    bf16x8 af[4], bfr[4];
    #pragma unroll
    for (int i = 0; i < 4; ++i)
      af[i] = *(const bf16x8*)&As[wr * 64 + i * 16 + ln][kq * 8];
    #pragma unroll
    for (int j = 0; j < 4; ++j)
      bfr[j] = *(const bf16x8*)&Bs[wc * 64 + j * 16 + ln][kq * 8];
    #pragma unroll
    for (int i = 0; i < 4; ++i)
      #pragma unroll
      for (int j = 0; j < 4; ++j)
        acc[i][j] = __builtin_amdgcn_mfma_f32_16x16x32_bf16(af[i], bfr[j], acc[i][j], 0, 0, 0);
    __syncthreads();
  }

  #pragma unroll
  for (int i = 0; i < 4; ++i) {
    const int ig = m0 + wr * 64 + i * 16 + kq * 4;
    #pragma unroll
    for (int j = 0; j < 4; ++j) {
      const int jg = n0 + wc * 64 + j * 16 + ln;
      f32x4 a = acc[i][j];
      if (qkv) {
        float bias = P.qkvb[jg];
        if (jg < 512) {
          bf16* d = P.qT + ((size_t)lb * NT + ig) * NC + jg;
          #pragma unroll
          for (int r = 0; r < 4; ++r) d[(size_t)r * NC] = __float2bfloat16(a[r] + bias);
        } else if (jg < 1024) {
          bf16* d = P.kfT + ((size_t)lb * NL + 256 + ig) * NC + (jg - 512);
          #pragma unroll
          for (int r = 0; r < 4; ++r) d[(size_t)r * NC] = __float2bfloat16(a[r] + bias);
        } else {
          u16x4 pk;
          #pragma unroll
          for (int r = 0; r < 4; ++r) pk[r] = f2bf_bits(a[r] + bias);
          *(u16x4*)(P.vf + ((size_t)lb * NC + (jg - 1024)) * NL + 256 + ig) = pk;
        }
      } else {  // EKV
        float bias = P.ekvb[jg];
        if (jg < 512) {
          bf16* d = P.kfT + ((size_t)lb * NL + ig) * NC + jg;
          #pragma unroll
          for (int r = 0; r < 4; ++r) d[(size_t)r * NC] = __float2bfloat16(a[r] + bias);
        } else {
          u16x4 pk;
          #pragma unroll
          for (int r = 0; r < 4; ++r) pk[r] = f2bf_bits(a[r] + bias);
          *(u16x4*)(P.vf + ((size_t)lb * NC + (jg - 512)) * NL + ig) = pk;
        }
      }
    }
  }
}

// ---- Fused QK^T + softmax -> P (in-place over qT) -------------------------
// Grid (nbc, 8): block = (batch, 32-row q-tile), 4 waves; wave w owns cols
// [w*128, w*128+128). S stays in registers; P overwrites this block's own
// q rows (exclusive ownership -> race-free). Kills the S f32 roundtrip.
__global__ __launch_bounds__(256) void att_sm_k(Params P) {
  __shared__ unsigned short Abuf[32][32];    // 2 KB  q-tile k-slice
  __shared__ unsigned short Bbuf[512][32];   // 32 KB full-N K k-slice
  __shared__ float redm[4][32];
  __shared__ float reds[4][32];

  const int lb = blockIdx.x;
  const int t0 = blockIdx.y * 32;
  const int tid = threadIdx.x;
  const int lane = tid & 63, w = tid >> 6;
  const int ln = lane & 15, kq = lane >> 4;
  const int srow = lane >> 2;          // staging row within 16
  const int scol = (lane & 3) * 16;    // staging byte offset within 64B row

  const char* qg = (const char*)(P.qT  + ((size_t)lb * NT + t0) * NC);
  const char* kg = (const char*)(P.kfT + (size_t)lb * NL * NC);

  f32x4 sa[2][8] = {};
  bf16x8 af[2], bfr[8];

  for (int k0 = 0; k0 < 512; k0 += 32) {
    const size_t koff = (size_t)k0 * 2 + scol;
    if (w < 2)
      gld16(qg + (size_t)(w * 16 + srow) * 1024 + koff, (char*)Abuf + w * 1024);
    #pragma unroll
    for (int h = 0; h < 8; ++h)
      gld16(kg + (size_t)(w * 128 + h * 16 + srow) * 1024 + koff,
            (char*)Bbuf + w * 8192 + h * 1024);
    __syncthreads();
    af[0] = *(const bf16x8*)&Abuf[ln][kq * 8];
    af[1] = *(const bf16x8*)&Abuf[16 + ln][kq * 8];
    #pragma unroll
    for (int j = 0; j < 8; ++j)
      bfr[j] = *(const bf16x8*)&Bbuf[w * 128 + j * 16 + ln][kq * 8];
    #pragma unroll
    for (int i = 0; i < 2; ++i)
      #pragma unroll
      for (int j = 0; j < 8; ++j)
        sa[i][j] = __builtin_amdgcn_mfma_f32_16x16x32_bf16(af[i], bfr[j], sa[i][j], 0, 0, 0);
    __syncthreads();
  }

  // ---- softmax over L=512 (rows: i*16 + kq*4 + r) ----
  float mx[2][4], sum[2][4], inv[2][4];
  #pragma unroll
  for (int i = 0; i < 2; ++i)
    #pragma unroll
    for (int r = 0; r < 4; ++r) {
      float m = -1e30f;
      #pragma unroll
      for (int j = 0; j < 8; ++j) m = fmaxf(m, sa[i][j][r]);
      mx[i][r] = m;
    }
  #pragma unroll
  for (int off = 1; off < 16; off <<= 1)
    #pragma unroll
    for (int i = 0; i < 2; ++i)
      #pragma unroll
      for (int r = 0; r < 4; ++r) mx[i][r] = fmaxf(mx[i][r], __shfl_xor(mx[i][r], off));
  if (ln == 0)
    #pragma unroll
    for (int i = 0; i < 2; ++i)
      #pragma unroll
      for (int r = 0; r < 4; ++r) redm[w][i * 16 + kq * 4 + r] = mx[i][r];
  __syncthreads();
  #pragma unroll
  for (int i = 0; i < 2; ++i)
    #pragma unroll
    for (int r = 0; r < 4; ++r) {
      const int row = i * 16 + kq * 4 + r;
      mx[i][r] = fmaxf(fmaxf(redm[0][row], redm[1][row]),
                       fmaxf(redm[2][row], redm[3][row]));
      sum[i][r] = 0.f;
    }
  #pragma unroll
  for (int i = 0; i < 2; ++i)
    #pragma unroll
    for (int j = 0; j < 8; ++j)
      #pragma unroll
      for (int r = 0; r < 4; ++r) {
        float e = __expf(SCALE2 * (sa[i][j][r] - mx[i][r]));
        sa[i][j][r] = e;
        sum[i][r] += e;
      }
  #pragma unroll
  for (int off = 1; off < 16; off <<= 1)
    #pragma unroll
    for (int i = 0; i < 2; ++i)
      #pragma unroll
      for (int r = 0; r < 4; ++r) sum[i][r] += __shfl_xor(sum[i][r], off);
  if (ln == 0)
    #pragma unroll
    for (int i = 0; i < 2; ++i)
      #pragma unroll
      for (int r = 0; r < 4; ++r) reds[w][i * 16 + kq * 4 + r] = sum[i][r];
  __syncthreads();
  #pragma unroll
  for (int i = 0; i < 2; ++i)
    #pragma unroll
    for (int r = 0; r < 4; ++r) {
      const int row = i * 16 + kq * 4 + r;
      inv[i][r] = 1.0f / (reds[0][row] + reds[1][row] + reds[2][row] + reds[3][row]);
    }

  // ---- P (bf16) in-place over this block's q rows ----
  bf16* pdst = P.qT + ((size_t)lb * NT + t0) * NL;
  #pragma unroll
  for (int i = 0; i < 2; ++i)
    #pragma unroll
    for (int j = 0; j < 8; ++j)
      #pragma unroll
      for (int r = 0; r < 4; ++r)
        pdst[(size_t)(i * 16 + kq * 4 + r) * NL + w * 128 + j * 16 + ln] =
            __float2bfloat16(sa[i][j][r] * inv[i][r]);
}

// ---- Attention tail GEMMs (same proven skeleton) --------------------------
// MODE 1: O = P . vf^T  (bf16 out, overlays kfT)
// MODE 2: Z = O . wp^T, fused epilogue out = 2*morph - x - (Z + projb)
template <int MODE>
__global__ __launch_bounds__(256) void gemm_att(Params P) {
  __shared__ unsigned short As[128][32];
  __shared__ unsigned short Bs[128][32];
  const int lb = blockIdx.x;
  const int m0 = blockIdx.y * 128;   // t-tile (M = 256)
  const int n0 = blockIdx.z * 128;   // col tile (N = 512)
  const int tid = threadIdx.x;
  const int lane = tid & 63, w = tid >> 6;
  const int wr = w >> 1, wc = w & 1;
  const int ln = lane & 15, kq = lane >> 4;

  const bf16 *Ab, *Bb;
  if (MODE == 1) { Ab = P.qT  + (size_t)lb * 131072; Bb = P.vf + (size_t)lb * NC * NL; }
  else           { Ab = P.kfT + (size_t)lb * 262144; Bb = P.wp; }

  const char* Abase = (const char*)(Ab + (size_t)m0 * 512);
  const char* Bbase = (const char*)(Bb + (size_t)n0 * 512);

  const int r_lo = w * 32 + (lane >> 2);
  const int cid16 = (lane & 3) * 16;

  f32x4 acc[4][4] = {};

  for (int k0 = 0; k0 < 512; k0 += 32) {
    const size_t kb = (size_t)k0 * 2 + cid16;
    #pragma unroll
    for (int h = 0; h < 2; ++h) {
      const int rw = r_lo + h * 16;
      gld16(Abase + (size_t)rw * 1024 + kb, (char*)As + w * 2048 + h * 1024);
      gld16(Bbase + (size_t)rw * 1024 + kb, (char*)Bs + w * 2048 + h * 1024);
    }
    __syncthreads();
    bf16x8 af[4], bfr[4];
    #pragma unroll
    for (int i = 0; i < 4; ++i)
      af[i] = *(const bf16x8*)&As[wr * 64 + i * 16 + ln][kq * 8];
    #pragma unroll
    for (int j = 0; j < 4; ++j)
      bfr[j] = *(const bf16x8*)&Bs[wc * 64 + j * 16 + ln][kq * 8];
    #pragma unroll
    for (int i = 0; i < 4; ++i)
      #pragma unroll
      for (int j = 0; j < 4; ++j)
        acc[i][j] = __builtin_amdgcn_mfma_f32_16x16x32_bf16(af[i], bfr[j], acc[i][j], 0, 0, 0);
    __syncthreads();
  }

  bf16* Og = P.kfT + (size_t)lb * 262144;                    // MODE 1 out
  const int gb = P.b0 + lb;                                  // MODE 2

  #pragma unroll
  for (int i = 0; i < 4; ++i) {
    const int ig = m0 + wr * 64 + i * 16 + kq * 4;
    #pragma unroll
    for (int j = 0; j < 4; ++j) {
      const int jg = n0 + wc * 64 + j * 16 + ln;
      f32x4 a = acc[i][j];
      if (MODE == 1) {
        bf16* d = Og + (size_t)ig * NC + jg;
        #pragma unroll
        for (int r = 0; r < 4; ++r) d[(size_t)r * NC] = __float2bfloat16(a[r]);
      } else {
        const float bias = P.projb[jg];
        const size_t idx = ((size_t)gb * NC + jg) * NT + ig;
        float4 mo = *(const float4*)&P.morph[idx];
        float4 xx = *(const float4*)&P.x[idx];
        f32x4 o;
        o[0] = 2.0f * mo.x - xx.x - (a[0] + bias);
        o[1] = 2.0f * mo.y - xx.y - (a[1] + bias);
        o[2] = 2.0f * mo.z - xx.z - (a[2] + bias);
        o[3] = 2.0f * mo.w - xx.w - (a[3] + bias);
        *(f32x4*)&P.out[idx] = o;
      }
    }
  }
}

extern "C" void kernel_launch(void* const* d_in, const int* in_sizes, int n_in,
                              void* d_out, int out_size, void* d_ws, size_t ws_size,
                              hipStream_t stream) {
  const float* x     = (const float*)d_in[0];
  const float* morph = (const float*)d_in[1];
  const float* gnw   = (const float*)d_in[2];
  const float* gnb   = (const float*)d_in[3];
  const float* qkvw  = (const float*)d_in[4];
  const float* qkvb  = (const float*)d_in[5];
  const float* ekvw  = (const float*)d_in[6];
  const float* ekvb  = (const float*)d_in[7];
  const float* projw = (const float*)d_in[8];
  const float* projb = (const float*)d_in[9];

  bf16* wq = (bf16*)d_ws;                // 786432
  bf16* we = wq + 786432;                // 524288
  bf16* wp = we + 524288;                // 262144
  float* stats = (float*)(wp + 262144);  // 8192 floats
  bf16* pb = (bf16*)(stats + 8192);

  // Per-batch bf16: hT 131072 + mT 131072 + qT 131072 + kfT 262144 + vf 262144
  const size_t per_b = 917504;
  const size_t fixed = (size_t)(786432 + 524288 + 262144) * 2 + 8192 * 4;
  int nbc = NB;
  while (nbc > 1 && fixed + (size_t)nbc * per_b * 2 > ws_size) nbc >>= 1;

  Params P;
  P.x = x; P.morph = morph; P.qkvb = qkvb; P.ekvb = ekvb; P.projb = projb;
  P.wq = wq; P.we = we; P.wp = wp;
  P.hT  = pb;  pb += (size_t)nbc * 131072;
  P.mT  = pb;  pb += (size_t)nbc * 131072;
  P.qT  = pb;  pb += (size_t)nbc * 131072;
  P.kfT = pb;  pb += (size_t)nbc * 262144;
  P.vf  = pb;
  P.out = (float*)d_out;

  gn_stats_k<<<dim3(NB * NG), dim3(256), 0, stream>>>(x, stats);
  cvt_k<<<dim3(3072), dim3(256), 0, stream>>>(qkvw, wq, 786432);
  cvt_k<<<dim3(2048), dim3(256), 0, stream>>>(ekvw, we, 524288);
  cvt_k<<<dim3(1024), dim3(256), 0, stream>>>(projw, wp, 262144);

  for (int b0 = 0; b0 < NB; b0 += nbc) {
    P.b0 = b0;
    transpose2_k<<<dim3(4, 8, 2 * nbc), dim3(256), 0, stream>>>(
        x, morph, P.hT, P.mT, stats, gnw, gnb, b0, nbc);
    gemm_in_k  <<<dim3(nbc, 2, 20), dim3(256), 0, stream>>>(P);
    att_sm_k   <<<dim3(nbc, 8),     dim3(256), 0, stream>>>(P);
    gemm_att<1><<<dim3(nbc, 2, 4),  dim3(256), 0, stream>>>(P);
    gemm_att<2><<<dim3(nbc, 2, 4),  dim3(256), 0, stream>>>(P);
  }
}